// Round 2
// baseline (1826.778 us; speedup 1.0000x reference)
//
#include <hip/hip_runtime.h>
#include <cstdint>
#include <cstddef>

typedef __bf16 bf16_t;
typedef __bf16 bf16x8 __attribute__((ext_vector_type(8)));
typedef float  f32x4  __attribute__((ext_vector_type(4)));

#define D_MODEL 768
#define D_INNER 1536
#define D_STATE 16
#define DT_RANK 48
#define NB      2
#define SEQ     2048
#define NTOK    (NB*SEQ)   // 4096
#define XPROJ_N (DT_RANK + 2*D_STATE)  // 80

// ---------------- fp32 -> bf16 conversion (weights) ----------------
__global__ __launch_bounds__(256)
void cvt_kernel(const float* __restrict__ src, bf16_t* __restrict__ dst, int n) {
    int i = blockIdx.x * 256 + threadIdx.x;
    if (i < n) dst[i] = (bf16_t)src[i];
}

// ---------------- RMSNorm: one block per token, fp32 in -> bf16 out ----------------
__global__ __launch_bounds__(256)
void rmsnorm_kernel(const float* __restrict__ x, const float* __restrict__ w,
                    bf16_t* __restrict__ h) {
    int t = blockIdx.x;
    int tid = threadIdx.x;
    const float* xr = x + (size_t)t * D_MODEL;
    float v[3];
    float ss = 0.f;
#pragma unroll
    for (int i = 0; i < 3; i++) { v[i] = xr[tid + 256*i]; ss += v[i]*v[i]; }
#pragma unroll
    for (int off = 32; off >= 1; off >>= 1) ss += __shfl_down(ss, off);
    __shared__ float red[4];
    int lane = tid & 63, wv = tid >> 6;
    if (lane == 0) red[wv] = ss;
    __syncthreads();
    float tot = red[0] + red[1] + red[2] + red[3];
    float r = rsqrtf(tot * (1.f/(float)D_MODEL) + 1e-5f);
#pragma unroll
    for (int i = 0; i < 3; i++)
        h[(size_t)t*D_MODEL + tid + 256*i] = (bf16_t)(v[i] * r * w[tid + 256*i]);
}

// ---------------- NT GEMM: C[m,n] = sum_k A[m,k]*B[n,k] ----------------
// 64x64 tile, 256 threads (4 waves), MFMA 16x16x32 bf16.
// Requirements: M % 64 == 0; lda, ldb multiples of 8 (true here).
// MODE 0: C(bf16) = acc
// MODE 1: C(bf16) = softplus(acc + bias[n])
// MODE 2: C(f32) = acc + resid[m,n]; resid_out[m,n] = resid[m,n]
template<int MODE>
__global__ __launch_bounds__(256)
void gemm_nt(const bf16_t* __restrict__ A, int lda,
             const bf16_t* __restrict__ B, int ldb,
             void* __restrict__ Cv, int ldc, int N, int K,
             const float* __restrict__ bias,
             const float* __restrict__ resid, float* __restrict__ resid_out) {
    __shared__ __align__(16) bf16_t As[64*32];
    __shared__ __align__(16) bf16_t Bs[64*32];
    const int tid = threadIdx.x;
    const int m0 = blockIdx.x * 64, n0 = blockIdx.y * 64;
    const int r  = tid >> 2, c8 = (tid & 3) << 3;   // staging: row, col-group of 8
    const int wave = tid >> 6, lane = tid & 63;
    const int quad = lane >> 4, l16 = lane & 15;

    f32x4 acc[4] = {{0.f,0.f,0.f,0.f},{0.f,0.f,0.f,0.f},
                    {0.f,0.f,0.f,0.f},{0.f,0.f,0.f,0.f}};

    for (int k0 = 0; k0 < K; k0 += 32) {
        int gk = k0 + c8;
        uint4 va = {0u,0u,0u,0u};
        if (gk + 8 <= K)
            va = *(const uint4*)(A + (size_t)(m0 + r) * lda + gk);
        *(uint4*)&As[r*32 + c8] = va;

        uint4 vb = {0u,0u,0u,0u};
        int nr = n0 + r;
        if (nr < N && gk + 8 <= K)
            vb = *(const uint4*)(B + (size_t)nr * ldb + gk);
        *(uint4*)&Bs[r*32 + c8] = vb;

        __syncthreads();
        // wave w computes rows [w*16, w*16+16) x all 64 cols
        bf16x8 af = *(const bf16x8*)&As[(wave*16 + l16)*32 + quad*8];
#pragma unroll
        for (int nt = 0; nt < 4; nt++) {
            bf16x8 bfg = *(const bf16x8*)&Bs[(nt*16 + l16)*32 + quad*8];
            acc[nt] = __builtin_amdgcn_mfma_f32_16x16x32_bf16(af, bfg, acc[nt], 0, 0, 0);
        }
        __syncthreads();
    }

#pragma unroll
    for (int nt = 0; nt < 4; nt++) {
        int n = n0 + nt*16 + l16;
        if (n >= N) continue;
#pragma unroll
        for (int rr = 0; rr < 4; rr++) {
            int m = m0 + wave*16 + quad*4 + rr;
            float v = acc[nt][rr];
            size_t idx = (size_t)m * ldc + n;
            if (MODE == 1) {
                float u = v + bias[n];
                float sp = (u > 20.f) ? u : log1pf(__expf(u));
                ((bf16_t*)Cv)[idx] = (bf16_t)sp;
            } else if (MODE == 2) {
                float rx = resid[idx];
                ((float*)Cv)[idx] = v + rx;
                resid_out[idx] = rx;
            } else {
                ((bf16_t*)Cv)[idx] = (bf16_t)v;
            }
        }
    }
}

// ---------------- causal depthwise conv(4) + SiLU ----------------
__global__ __launch_bounds__(256)
void conv_silu_kernel(const bf16_t* __restrict__ xz,
                      const float* __restrict__ cw,
                      const float* __restrict__ cb,
                      bf16_t* __restrict__ xc) {
    int t = blockIdx.x;        // global token
    int l = t & (SEQ - 1);     // position within sequence
    for (int d = threadIdx.x; d < D_INNER; d += 256) {
        float acc = cb[d];
#pragma unroll
        for (int k = 0; k < 4; k++) {
            int ll = l - 3 + k;
            if (ll >= 0)
                acc += (float)xz[(size_t)(t - 3 + k) * (2*D_INNER) + d] * cw[d*4 + k];
        }
        float s = acc / (1.f + __expf(-acc));
        xc[(size_t)t * D_INNER + d] = (bf16_t)s;
    }
}

// ---------------- selective scan ----------------
// one thread per (b, d, n); 16-lane shfl_xor reduction over n; lane n==0
// applies D-skip + SiLU(z) gate and writes y.
__global__ __launch_bounds__(256)
void scan_kernel(const bf16_t* __restrict__ delta,
                 const bf16_t* __restrict__ xc,
                 const bf16_t* __restrict__ proj,
                 const bf16_t* __restrict__ xz,
                 const float* __restrict__ A_log,
                 const float* __restrict__ Dw,
                 bf16_t* __restrict__ y) {
    const int tid = threadIdx.x;
    const int n = tid & 15;
    const int d = blockIdx.x * 16 + (tid >> 4);
    const int b = blockIdx.y;
    const float Av = -__expf(A_log[d*D_STATE + n]);
    const float Dv = Dw[d];
    float s = 0.f;
    for (int l = 0; l < SEQ; l++) {
        size_t t = (size_t)b * SEQ + l;
        float dv  = (float)delta[t*D_INNER + d];
        float xcv = (float)xc[t*D_INNER + d];
        float Bv  = (float)proj[t*XPROJ_N + DT_RANK + n];
        float Cv  = (float)proj[t*XPROJ_N + DT_RANK + D_STATE + n];
        s = __expf(dv * Av) * s + (dv * Bv) * xcv;
        float part = s * Cv;
        part += __shfl_xor(part, 1);
        part += __shfl_xor(part, 2);
        part += __shfl_xor(part, 4);
        part += __shfl_xor(part, 8);
        if (n == 0) {
            float zf = (float)xz[t*(2*D_INNER) + D_INNER + d];
            float g = zf / (1.f + __expf(-zf));
            y[t*D_INNER + d] = (bf16_t)((part + xcv * Dv) * g);
        }
    }
}

extern "C" void kernel_launch(void* const* d_in, const int* in_sizes, int n_in,
                              void* d_out, int out_size, void* d_ws, size_t ws_size,
                              hipStream_t stream) {
    const float* x          = (const float*)d_in[0];
    const float* norm_w     = (const float*)d_in[1];
    const float* in_proj_w  = (const float*)d_in[2];
    const float* conv_w     = (const float*)d_in[3];
    const float* conv_b     = (const float*)d_in[4];
    const float* x_proj_w   = (const float*)d_in[5];
    const float* dt_proj_w  = (const float*)d_in[6];
    const float* dt_proj_b  = (const float*)d_in[7];
    const float* A_log      = (const float*)d_in[8];
    const float* Dw         = (const float*)d_in[9];
    const float* out_proj_w = (const float*)d_in[10];

    float* out0 = (float*)d_out;                       // x + out_proj(y)
    float* out1 = out0 + (size_t)NTOK * D_MODEL;       // residual copy

    const int n_inw = 2*D_INNER*D_MODEL;   // 2359296
    const int n_xpw = XPROJ_N*D_INNER;     // 122880
    const int n_dtw = D_INNER*DT_RANK;     // 73728
    const int n_opw = D_MODEL*D_INNER;     // 1179648

    char* ws = (char*)d_ws;
    bf16_t* w_in  = (bf16_t*)ws;  ws += (size_t)n_inw * sizeof(bf16_t);
    bf16_t* w_xp  = (bf16_t*)ws;  ws += (size_t)n_xpw * sizeof(bf16_t);
    bf16_t* w_dt  = (bf16_t*)ws;  ws += (size_t)n_dtw * sizeof(bf16_t);
    bf16_t* w_op  = (bf16_t*)ws;  ws += (size_t)n_opw * sizeof(bf16_t);
    bf16_t* h     = (bf16_t*)ws;  ws += (size_t)NTOK * D_MODEL   * sizeof(bf16_t);
    bf16_t* xz    = (bf16_t*)ws;  ws += (size_t)NTOK * 2*D_INNER * sizeof(bf16_t);
    bf16_t* xc    = (bf16_t*)ws;  ws += (size_t)NTOK * D_INNER   * sizeof(bf16_t);
    bf16_t* proj  = (bf16_t*)ws;  ws += (size_t)NTOK * XPROJ_N   * sizeof(bf16_t);
    bf16_t* delta = (bf16_t*)ws;  ws += (size_t)NTOK * D_INNER   * sizeof(bf16_t);
    bf16_t* y     = (bf16_t*)ws;  ws += (size_t)NTOK * D_INNER   * sizeof(bf16_t);

    // 0) weight fp32 -> bf16
    cvt_kernel<<<(n_inw+255)/256, 256, 0, stream>>>(in_proj_w,  w_in, n_inw);
    cvt_kernel<<<(n_xpw+255)/256, 256, 0, stream>>>(x_proj_w,   w_xp, n_xpw);
    cvt_kernel<<<(n_dtw+255)/256, 256, 0, stream>>>(dt_proj_w,  w_dt, n_dtw);
    cvt_kernel<<<(n_opw+255)/256, 256, 0, stream>>>(out_proj_w, w_op, n_opw);

    // 1) RMSNorm (fp32 -> bf16)
    rmsnorm_kernel<<<NTOK, 256, 0, stream>>>(x, norm_w, h);
    // 2) in_proj: [4096,768] x [3072,768]^T -> xz [4096,3072]
    gemm_nt<0><<<dim3(NTOK/64, (2*D_INNER)/64), 256, 0, stream>>>(
        h, D_MODEL, w_in, D_MODEL, xz, 2*D_INNER, 2*D_INNER, D_MODEL,
        nullptr, nullptr, nullptr);
    // 3) causal depthwise conv + SiLU -> xc [4096,1536]
    conv_silu_kernel<<<NTOK, 256, 0, stream>>>(xz, conv_w, conv_b, xc);
    // 4) x_proj: [4096,1536] x [80,1536]^T -> proj [4096,80]
    gemm_nt<0><<<dim3(NTOK/64, 2), 256, 0, stream>>>(
        xc, D_INNER, w_xp, D_INNER, proj, XPROJ_N, XPROJ_N, D_INNER,
        nullptr, nullptr, nullptr);
    // 5) dt_proj + softplus: [4096,48(of 80)] x [1536,48]^T -> delta [4096,1536]
    gemm_nt<1><<<dim3(NTOK/64, D_INNER/64), 256, 0, stream>>>(
        proj, XPROJ_N, w_dt, DT_RANK, delta, D_INNER, D_INNER, DT_RANK,
        dt_proj_b, nullptr, nullptr);
    // 6) selective scan + D-skip + gate -> y [4096,1536]
    scan_kernel<<<dim3(D_INNER/16, NB), 256, 0, stream>>>(
        delta, xc, proj, xz, A_log, Dw, y);
    // 7) out_proj + residual add (fp32 out); also emit residual copy
    gemm_nt<2><<<dim3(NTOK/64, D_MODEL/64), 256, 0, stream>>>(
        y, D_INNER, w_op, D_INNER, out0, D_MODEL, D_MODEL, D_INNER,
        nullptr, x, out1);
}

// Round 3
// 582.515 us; speedup vs baseline: 3.1360x; 3.1360x over previous
//
#include <hip/hip_runtime.h>
#include <cstdint>
#include <cstddef>

typedef __bf16 bf16_t;
typedef __bf16 bf16x8 __attribute__((ext_vector_type(8)));
typedef float  f32x4  __attribute__((ext_vector_type(4)));

#define D_MODEL 768
#define D_INNER 1536
#define D_STATE 16
#define DT_RANK 48
#define NB      2
#define SEQ     2048
#define NTOK    (NB*SEQ)   // 4096
#define XPROJ_N (DT_RANK + 2*D_STATE)  // 80
#define LC      128
#define NCHUNK  (SEQ/LC)   // 16

// ---------------- fp32 -> bf16 conversion (weights) ----------------
__global__ __launch_bounds__(256)
void cvt_kernel(const float* __restrict__ src, bf16_t* __restrict__ dst, int n) {
    int i = blockIdx.x * 256 + threadIdx.x;
    if (i < n) dst[i] = (bf16_t)src[i];
}

// ---------------- RMSNorm: one block per token, fp32 in -> bf16 out ----------------
__global__ __launch_bounds__(256)
void rmsnorm_kernel(const float* __restrict__ x, const float* __restrict__ w,
                    bf16_t* __restrict__ h) {
    int t = blockIdx.x;
    int tid = threadIdx.x;
    const float* xr = x + (size_t)t * D_MODEL;
    float v[3];
    float ss = 0.f;
#pragma unroll
    for (int i = 0; i < 3; i++) { v[i] = xr[tid + 256*i]; ss += v[i]*v[i]; }
#pragma unroll
    for (int off = 32; off >= 1; off >>= 1) ss += __shfl_down(ss, off);
    __shared__ float red[4];
    int lane = tid & 63, wv = tid >> 6;
    if (lane == 0) red[wv] = ss;
    __syncthreads();
    float tot = red[0] + red[1] + red[2] + red[3];
    float r = rsqrtf(tot * (1.f/(float)D_MODEL) + 1e-5f);
#pragma unroll
    for (int i = 0; i < 3; i++)
        h[(size_t)t*D_MODEL + tid + 256*i] = (bf16_t)(v[i] * r * w[tid + 256*i]);
}

// ---------------- NT GEMM: C[m,n] = sum_k A[m,k]*B[n,k] ----------------
// 64x64 tile, 256 threads (4 waves), MFMA 16x16x32 bf16.
// MODE 0: C(bf16) = acc
// MODE 1: C(bf16) = softplus(acc + bias[n])
// MODE 2: C(f32) = acc + resid[m,n]; resid_out[m,n] = resid[m,n]
template<int MODE>
__global__ __launch_bounds__(256)
void gemm_nt(const bf16_t* __restrict__ A, int lda,
             const bf16_t* __restrict__ B, int ldb,
             void* __restrict__ Cv, int ldc, int N, int K,
             const float* __restrict__ bias,
             const float* __restrict__ resid, float* __restrict__ resid_out) {
    __shared__ __align__(16) bf16_t As[64*32];
    __shared__ __align__(16) bf16_t Bs[64*32];
    const int tid = threadIdx.x;
    const int m0 = blockIdx.x * 64, n0 = blockIdx.y * 64;
    const int r  = tid >> 2, c8 = (tid & 3) << 3;
    const int wave = tid >> 6, lane = tid & 63;
    const int quad = lane >> 4, l16 = lane & 15;

    f32x4 acc[4] = {{0.f,0.f,0.f,0.f},{0.f,0.f,0.f,0.f},
                    {0.f,0.f,0.f,0.f},{0.f,0.f,0.f,0.f}};

    for (int k0 = 0; k0 < K; k0 += 32) {
        int gk = k0 + c8;
        uint4 va = {0u,0u,0u,0u};
        if (gk + 8 <= K)
            va = *(const uint4*)(A + (size_t)(m0 + r) * lda + gk);
        *(uint4*)&As[r*32 + c8] = va;

        uint4 vb = {0u,0u,0u,0u};
        int nr = n0 + r;
        if (nr < N && gk + 8 <= K)
            vb = *(const uint4*)(B + (size_t)nr * ldb + gk);
        *(uint4*)&Bs[r*32 + c8] = vb;

        __syncthreads();
        bf16x8 af = *(const bf16x8*)&As[(wave*16 + l16)*32 + quad*8];
#pragma unroll
        for (int nt = 0; nt < 4; nt++) {
            bf16x8 bfg = *(const bf16x8*)&Bs[(nt*16 + l16)*32 + quad*8];
            acc[nt] = __builtin_amdgcn_mfma_f32_16x16x32_bf16(af, bfg, acc[nt], 0, 0, 0);
        }
        __syncthreads();
    }

#pragma unroll
    for (int nt = 0; nt < 4; nt++) {
        int n = n0 + nt*16 + l16;
        if (n >= N) continue;
#pragma unroll
        for (int rr = 0; rr < 4; rr++) {
            int m = m0 + wave*16 + quad*4 + rr;
            float v = acc[nt][rr];
            size_t idx = (size_t)m * ldc + n;
            if (MODE == 1) {
                float u = v + bias[n];
                float sp = (u > 20.f) ? u : log1pf(__expf(u));
                ((bf16_t*)Cv)[idx] = (bf16_t)sp;
            } else if (MODE == 2) {
                float rx = resid[idx];
                ((float*)Cv)[idx] = v + rx;
                resid_out[idx] = rx;
            } else {
                ((bf16_t*)Cv)[idx] = (bf16_t)v;
            }
        }
    }
}

// ---------------- causal depthwise conv(4) + SiLU ----------------
__global__ __launch_bounds__(256)
void conv_silu_kernel(const bf16_t* __restrict__ xz,
                      const float* __restrict__ cw,
                      const float* __restrict__ cb,
                      bf16_t* __restrict__ xc) {
    int t = blockIdx.x;
    int l = t & (SEQ - 1);
    for (int d = threadIdx.x; d < D_INNER; d += 256) {
        float acc = cb[d];
#pragma unroll
        for (int k = 0; k < 4; k++) {
            int ll = l - 3 + k;
            if (ll >= 0)
                acc += (float)xz[(size_t)(t - 3 + k) * (2*D_INNER) + d] * cw[d*4 + k];
        }
        float s = acc / (1.f + __expf(-acc));
        xc[(size_t)t * D_INNER + d] = (bf16_t)s;
    }
}

// ---------------- chunked selective scan ----------------
// Recurrence h_t = a_t*h_{t-1} + b_t, a_t = exp(delta*A), b_t = delta*B_t*xc.
// Phase 1: per-chunk local scan from 0 + coefficient product P = prod(a_t).
// Phase 2: sequential combine over the 16 chunks -> per-chunk initial state.
// Phase 3: re-run local scan seeded with initial state, emit y (C-reduce,
//          D-skip, SiLU(z) gate).
__global__ __launch_bounds__(256)
void scan_part1(const bf16_t* __restrict__ delta,
                const bf16_t* __restrict__ xc,
                const bf16_t* __restrict__ proj,
                const float* __restrict__ A_log,
                float* __restrict__ chunk_h, float* __restrict__ chunk_P) {
    const int tid = threadIdx.x;
    const int n = tid & 15;
    const int d = blockIdx.x * 16 + (tid >> 4);
    const int c = blockIdx.y;
    const int b = blockIdx.z;
    const float Av = -__expf(A_log[d*D_STATE + n]);
    float s = 0.f, P = 1.f;
    for (int l = c*LC; l < (c+1)*LC; l++) {
        size_t t = (size_t)b * SEQ + l;
        float dv  = (float)delta[t*D_INNER + d];
        float xcv = (float)xc[t*D_INNER + d];
        float Bv  = (float)proj[t*XPROJ_N + DT_RANK + n];
        float a = __expf(dv * Av);
        s = a * s + (dv * Bv) * xcv;
        P *= a;
    }
    size_t idx = (((size_t)b*NCHUNK + c)*D_INNER + d)*D_STATE + n;
    chunk_h[idx] = s;
    chunk_P[idx] = P;
}

__global__ __launch_bounds__(256)
void scan_part2(float* __restrict__ chunk_h, const float* __restrict__ chunk_P) {
    int gid = blockIdx.x * 256 + threadIdx.x;      // b*(Di*N) + d*N + n
    int b  = gid / (D_INNER * D_STATE);
    int dn = gid - b * (D_INNER * D_STATE);
    float H = 0.f;
    for (int c = 0; c < NCHUNK; c++) {
        size_t idx = ((size_t)b*NCHUNK + c)*D_INNER*D_STATE + dn;
        float S = chunk_h[idx];
        float P = chunk_P[idx];
        chunk_h[idx] = H;          // becomes the initial state for chunk c
        H = P * H + S;
    }
}

__global__ __launch_bounds__(256)
void scan_part3(const bf16_t* __restrict__ delta,
                const bf16_t* __restrict__ xc,
                const bf16_t* __restrict__ proj,
                const bf16_t* __restrict__ xz,
                const float* __restrict__ A_log,
                const float* __restrict__ Dw,
                const float* __restrict__ chunk_h,
                bf16_t* __restrict__ y) {
    const int tid = threadIdx.x;
    const int n = tid & 15;
    const int d = blockIdx.x * 16 + (tid >> 4);
    const int c = blockIdx.y;
    const int b = blockIdx.z;
    const float Av = -__expf(A_log[d*D_STATE + n]);
    const float Dv = Dw[d];
    float s = chunk_h[(((size_t)b*NCHUNK + c)*D_INNER + d)*D_STATE + n];
    for (int l = c*LC; l < (c+1)*LC; l++) {
        size_t t = (size_t)b * SEQ + l;
        float dv  = (float)delta[t*D_INNER + d];
        float xcv = (float)xc[t*D_INNER + d];
        float Bv  = (float)proj[t*XPROJ_N + DT_RANK + n];
        float Cv  = (float)proj[t*XPROJ_N + DT_RANK + D_STATE + n];
        s = __expf(dv * Av) * s + (dv * Bv) * xcv;
        float part = s * Cv;
        part += __shfl_xor(part, 1);
        part += __shfl_xor(part, 2);
        part += __shfl_xor(part, 4);
        part += __shfl_xor(part, 8);
        if (n == 0) {
            float zf = (float)xz[t*(2*D_INNER) + D_INNER + d];
            float g = zf / (1.f + __expf(-zf));
            y[t*D_INNER + d] = (bf16_t)((part + xcv * Dv) * g);
        }
    }
}

extern "C" void kernel_launch(void* const* d_in, const int* in_sizes, int n_in,
                              void* d_out, int out_size, void* d_ws, size_t ws_size,
                              hipStream_t stream) {
    const float* x          = (const float*)d_in[0];
    const float* norm_w     = (const float*)d_in[1];
    const float* in_proj_w  = (const float*)d_in[2];
    const float* conv_w     = (const float*)d_in[3];
    const float* conv_b     = (const float*)d_in[4];
    const float* x_proj_w   = (const float*)d_in[5];
    const float* dt_proj_w  = (const float*)d_in[6];
    const float* dt_proj_b  = (const float*)d_in[7];
    const float* A_log      = (const float*)d_in[8];
    const float* Dw         = (const float*)d_in[9];
    const float* out_proj_w = (const float*)d_in[10];

    float* out0 = (float*)d_out;                       // x + out_proj(y)
    float* out1 = out0 + (size_t)NTOK * D_MODEL;       // residual copy

    const int n_inw = 2*D_INNER*D_MODEL;
    const int n_xpw = XPROJ_N*D_INNER;
    const int n_dtw = D_INNER*DT_RANK;
    const int n_opw = D_MODEL*D_INNER;
    const size_t n_chunkst = (size_t)NB*NCHUNK*D_INNER*D_STATE;  // 786432

    char* ws = (char*)d_ws;
    bf16_t* w_in  = (bf16_t*)ws;  ws += (size_t)n_inw * sizeof(bf16_t);
    bf16_t* w_xp  = (bf16_t*)ws;  ws += (size_t)n_xpw * sizeof(bf16_t);
    bf16_t* w_dt  = (bf16_t*)ws;  ws += (size_t)n_dtw * sizeof(bf16_t);
    bf16_t* w_op  = (bf16_t*)ws;  ws += (size_t)n_opw * sizeof(bf16_t);
    bf16_t* h     = (bf16_t*)ws;  ws += (size_t)NTOK * D_MODEL   * sizeof(bf16_t);
    bf16_t* xz    = (bf16_t*)ws;  ws += (size_t)NTOK * 2*D_INNER * sizeof(bf16_t);
    bf16_t* xc    = (bf16_t*)ws;  ws += (size_t)NTOK * D_INNER   * sizeof(bf16_t);
    bf16_t* proj  = (bf16_t*)ws;  ws += (size_t)NTOK * XPROJ_N   * sizeof(bf16_t);
    bf16_t* delta = (bf16_t*)ws;  ws += (size_t)NTOK * D_INNER   * sizeof(bf16_t);
    bf16_t* y     = (bf16_t*)ws;  ws += (size_t)NTOK * D_INNER   * sizeof(bf16_t);
    float*  ch    = (float*)ws;   ws += n_chunkst * sizeof(float);
    float*  cP    = (float*)ws;   ws += n_chunkst * sizeof(float);

    // 0) weight fp32 -> bf16
    cvt_kernel<<<(n_inw+255)/256, 256, 0, stream>>>(in_proj_w,  w_in, n_inw);
    cvt_kernel<<<(n_xpw+255)/256, 256, 0, stream>>>(x_proj_w,   w_xp, n_xpw);
    cvt_kernel<<<(n_dtw+255)/256, 256, 0, stream>>>(dt_proj_w,  w_dt, n_dtw);
    cvt_kernel<<<(n_opw+255)/256, 256, 0, stream>>>(out_proj_w, w_op, n_opw);

    // 1) RMSNorm
    rmsnorm_kernel<<<NTOK, 256, 0, stream>>>(x, norm_w, h);
    // 2) in_proj
    gemm_nt<0><<<dim3(NTOK/64, (2*D_INNER)/64), 256, 0, stream>>>(
        h, D_MODEL, w_in, D_MODEL, xz, 2*D_INNER, 2*D_INNER, D_MODEL,
        nullptr, nullptr, nullptr);
    // 3) conv + SiLU
    conv_silu_kernel<<<NTOK, 256, 0, stream>>>(xz, conv_w, conv_b, xc);
    // 4) x_proj
    gemm_nt<0><<<dim3(NTOK/64, 2), 256, 0, stream>>>(
        xc, D_INNER, w_xp, D_INNER, proj, XPROJ_N, XPROJ_N, D_INNER,
        nullptr, nullptr, nullptr);
    // 5) dt_proj + softplus
    gemm_nt<1><<<dim3(NTOK/64, D_INNER/64), 256, 0, stream>>>(
        proj, XPROJ_N, w_dt, DT_RANK, delta, D_INNER, D_INNER, DT_RANK,
        dt_proj_b, nullptr, nullptr);
    // 6) chunked selective scan
    scan_part1<<<dim3(D_INNER/16, NCHUNK, NB), 256, 0, stream>>>(
        delta, xc, proj, A_log, ch, cP);
    scan_part2<<<(int)(n_chunkst/256), 256, 0, stream>>>(ch, cP);
    scan_part3<<<dim3(D_INNER/16, NCHUNK, NB), 256, 0, stream>>>(
        delta, xc, proj, xz, A_log, Dw, ch, y);
    // 7) out_proj + residual add; residual copy
    gemm_nt<2><<<dim3(NTOK/64, D_MODEL/64), 256, 0, stream>>>(
        y, D_INNER, w_op, D_INNER, out0, D_MODEL, D_MODEL, D_INNER,
        nullptr, x, out1);
}

// Round 4
// 418.055 us; speedup vs baseline: 4.3697x; 1.3934x over previous
//
#include <hip/hip_runtime.h>
#include <cstdint>
#include <cstddef>

typedef __bf16 bf16_t;
typedef __bf16 bf16x8 __attribute__((ext_vector_type(8)));
typedef float  f32x4  __attribute__((ext_vector_type(4)));

#define D_MODEL 768
#define D_INNER 1536
#define D_STATE 16
#define DT_RANK 48
#define NB      2
#define SEQ     2048
#define NTOK    (NB*SEQ)   // 4096
#define XPROJ_N (DT_RANK + 2*D_STATE)  // 80
#define LC      64
#define NCHUNK  (SEQ/LC)   // 32

// ---------------- fp32 -> bf16 conversion (weights) ----------------
__global__ __launch_bounds__(256)
void cvt_kernel(const float* __restrict__ src, bf16_t* __restrict__ dst, int n) {
    int i = blockIdx.x * 256 + threadIdx.x;
    if (i < n) dst[i] = (bf16_t)src[i];
}

// ---------------- RMSNorm: one block per token, fp32 in -> bf16 out ----------------
__global__ __launch_bounds__(256)
void rmsnorm_kernel(const float* __restrict__ x, const float* __restrict__ w,
                    bf16_t* __restrict__ h) {
    int t = blockIdx.x;
    int tid = threadIdx.x;
    const float* xr = x + (size_t)t * D_MODEL;
    float v[3];
    float ss = 0.f;
#pragma unroll
    for (int i = 0; i < 3; i++) { v[i] = xr[tid + 256*i]; ss += v[i]*v[i]; }
#pragma unroll
    for (int off = 32; off >= 1; off >>= 1) ss += __shfl_down(ss, off);
    __shared__ float red[4];
    int lane = tid & 63, wv = tid >> 6;
    if (lane == 0) red[wv] = ss;
    __syncthreads();
    float tot = red[0] + red[1] + red[2] + red[3];
    float r = rsqrtf(tot * (1.f/(float)D_MODEL) + 1e-5f);
#pragma unroll
    for (int i = 0; i < 3; i++)
        h[(size_t)t*D_MODEL + tid + 256*i] = (bf16_t)(v[i] * r * w[tid + 256*i]);
}

// ---------------- NT GEMM: C[m,n] = sum_k A[m,k]*B[n,k] ----------------
// 64x64 tile, 256 threads (4 waves), MFMA 16x16x32 bf16.
// MODE 0: C(bf16) = acc
// MODE 1: C(bf16) = softplus(acc + bias[n])
// MODE 2: C(f32) = acc + resid[m,n]; resid_out[m,n] = resid[m,n]
template<int MODE>
__global__ __launch_bounds__(256)
void gemm_nt(const bf16_t* __restrict__ A, int lda,
             const bf16_t* __restrict__ B, int ldb,
             void* __restrict__ Cv, int ldc, int N, int K,
             const float* __restrict__ bias,
             const float* __restrict__ resid, float* __restrict__ resid_out) {
    __shared__ __align__(16) bf16_t As[64*32];
    __shared__ __align__(16) bf16_t Bs[64*32];
    const int tid = threadIdx.x;
    const int m0 = blockIdx.x * 64, n0 = blockIdx.y * 64;
    const int r  = tid >> 2, c8 = (tid & 3) << 3;
    const int wave = tid >> 6, lane = tid & 63;
    const int quad = lane >> 4, l16 = lane & 15;

    f32x4 acc[4] = {{0.f,0.f,0.f,0.f},{0.f,0.f,0.f,0.f},
                    {0.f,0.f,0.f,0.f},{0.f,0.f,0.f,0.f}};

    for (int k0 = 0; k0 < K; k0 += 32) {
        int gk = k0 + c8;
        uint4 va = {0u,0u,0u,0u};
        if (gk + 8 <= K)
            va = *(const uint4*)(A + (size_t)(m0 + r) * lda + gk);
        *(uint4*)&As[r*32 + c8] = va;

        uint4 vb = {0u,0u,0u,0u};
        int nr = n0 + r;
        if (nr < N && gk + 8 <= K)
            vb = *(const uint4*)(B + (size_t)nr * ldb + gk);
        *(uint4*)&Bs[r*32 + c8] = vb;

        __syncthreads();
        bf16x8 af = *(const bf16x8*)&As[(wave*16 + l16)*32 + quad*8];
#pragma unroll
        for (int nt = 0; nt < 4; nt++) {
            bf16x8 bfg = *(const bf16x8*)&Bs[(nt*16 + l16)*32 + quad*8];
            acc[nt] = __builtin_amdgcn_mfma_f32_16x16x32_bf16(af, bfg, acc[nt], 0, 0, 0);
        }
        __syncthreads();
    }

#pragma unroll
    for (int nt = 0; nt < 4; nt++) {
        int n = n0 + nt*16 + l16;
        if (n >= N) continue;
#pragma unroll
        for (int rr = 0; rr < 4; rr++) {
            int m = m0 + wave*16 + quad*4 + rr;
            float v = acc[nt][rr];
            size_t idx = (size_t)m * ldc + n;
            if (MODE == 1) {
                float u = v + bias[n];
                float sp = (u > 20.f) ? u : log1pf(__expf(u));
                ((bf16_t*)Cv)[idx] = (bf16_t)sp;
            } else if (MODE == 2) {
                float rx = resid[idx];
                ((float*)Cv)[idx] = v + rx;
                resid_out[idx] = rx;
            } else {
                ((bf16_t*)Cv)[idx] = (bf16_t)v;
            }
        }
    }
}

// ---------------- causal depthwise conv(4) + SiLU ----------------
__global__ __launch_bounds__(256)
void conv_silu_kernel(const bf16_t* __restrict__ xz,
                      const float* __restrict__ cw,
                      const float* __restrict__ cb,
                      bf16_t* __restrict__ xc) {
    int t = blockIdx.x;
    int l = t & (SEQ - 1);
    for (int d = threadIdx.x; d < D_INNER; d += 256) {
        float acc = cb[d];
#pragma unroll
        for (int k = 0; k < 4; k++) {
            int ll = l - 3 + k;
            if (ll >= 0)
                acc += (float)xz[(size_t)(t - 3 + k) * (2*D_INNER) + d] * cw[d*4 + k];
        }
        float s = acc / (1.f + __expf(-acc));
        xc[(size_t)t * D_INNER + d] = (bf16_t)s;
    }
}

// ---------------- chunked selective scan, 16 states/thread ----------------
// h_t[n] = exp(delta_t * A[n]) * h_{t-1}[n] + delta_t * B_t[n] * xc_t
// Phase 1: per-chunk local scan from 0 + per-state coefficient product P.
// Phase 2: sequential combine over chunks -> per-chunk initial states.
// Phase 3: re-run local scan seeded with init state; y = C·h + D-skip, gated.
// Thread = (b, c, d); all 16 n-states live in VGPRs (ILP=16, no shfl,
// coalesced activation loads, B/C rows broadcast from LDS as float).
__global__ __launch_bounds__(256)
void scan_part1(const bf16_t* __restrict__ delta,
                const bf16_t* __restrict__ xc,
                const bf16_t* __restrict__ proj,
                const float* __restrict__ A_log,
                float* __restrict__ chunk_h, float* __restrict__ chunk_P) {
    const int tid = threadIdx.x;
    const int d = blockIdx.x * 256 + tid;
    const int c = blockIdx.y;
    const int b = blockIdx.z;
    __shared__ float Bs[LC][D_STATE];
    for (int i = tid; i < LC*D_STATE; i += 256) {
        int l = i >> 4, n = i & 15;
        size_t t = (size_t)b*SEQ + (size_t)c*LC + l;
        Bs[l][n] = (float)proj[t*XPROJ_N + DT_RANK + n];
    }
    __syncthreads();
    float Av2[D_STATE];
#pragma unroll
    for (int n = 0; n < D_STATE; n++)
        Av2[n] = -__expf(A_log[d*D_STATE + n]) * 1.44269504f;   // A[n]*log2(e)
    float s[D_STATE], P[D_STATE];
#pragma unroll
    for (int n = 0; n < D_STATE; n++) { s[n] = 0.f; P[n] = 1.f; }
    const size_t tbase = (size_t)b*SEQ + (size_t)c*LC;
    for (int l = 0; l < LC; l++) {
        size_t t = tbase + l;
        float dv  = (float)delta[t*D_INNER + d];
        float xcv = (float)xc[t*D_INNER + d];
        float dx = dv * xcv;
#pragma unroll
        for (int n = 0; n < D_STATE; n++) {
            float a = exp2f(dv * Av2[n]);
            s[n] = a * s[n] + dx * Bs[l][n];
            P[n] *= a;
        }
    }
    size_t base = (((size_t)b*NCHUNK + c)*D_INNER + d)*D_STATE;
#pragma unroll
    for (int n = 0; n < D_STATE; n++) {
        chunk_h[base + n] = s[n];
        chunk_P[base + n] = P[n];
    }
}

__global__ __launch_bounds__(256)
void scan_part2(float* __restrict__ chunk_h, const float* __restrict__ chunk_P) {
    int gid = blockIdx.x * 256 + threadIdx.x;      // b*(Di*N) + d*N + n
    int b  = gid / (D_INNER * D_STATE);
    int dn = gid - b * (D_INNER * D_STATE);
    float H = 0.f;
    for (int c = 0; c < NCHUNK; c++) {
        size_t idx = ((size_t)b*NCHUNK + c)*D_INNER*D_STATE + dn;
        float S = chunk_h[idx];
        float P = chunk_P[idx];
        chunk_h[idx] = H;          // becomes the initial state for chunk c
        H = P * H + S;
    }
}

__global__ __launch_bounds__(256)
void scan_part3(const bf16_t* __restrict__ delta,
                const bf16_t* __restrict__ xc,
                const bf16_t* __restrict__ proj,
                const bf16_t* __restrict__ xz,
                const float* __restrict__ A_log,
                const float* __restrict__ Dw,
                const float* __restrict__ chunk_h,
                bf16_t* __restrict__ y) {
    const int tid = threadIdx.x;
    const int d = blockIdx.x * 256 + tid;
    const int c = blockIdx.y;
    const int b = blockIdx.z;
    __shared__ float Bs[LC][D_STATE];
    __shared__ float Cs[LC][D_STATE];
    for (int i = tid; i < LC*D_STATE; i += 256) {
        int l = i >> 4, n = i & 15;
        size_t t = (size_t)b*SEQ + (size_t)c*LC + l;
        Bs[l][n] = (float)proj[t*XPROJ_N + DT_RANK + n];
        Cs[l][n] = (float)proj[t*XPROJ_N + DT_RANK + D_STATE + n];
    }
    __syncthreads();
    float Av2[D_STATE];
#pragma unroll
    for (int n = 0; n < D_STATE; n++)
        Av2[n] = -__expf(A_log[d*D_STATE + n]) * 1.44269504f;
    const float Dv = Dw[d];
    float s[D_STATE];
    size_t base = (((size_t)b*NCHUNK + c)*D_INNER + d)*D_STATE;
#pragma unroll
    for (int n = 0; n < D_STATE; n++) s[n] = chunk_h[base + n];
    const size_t tbase = (size_t)b*SEQ + (size_t)c*LC;
    for (int l = 0; l < LC; l++) {
        size_t t = tbase + l;
        float dv  = (float)delta[t*D_INNER + d];
        float xcv = (float)xc[t*D_INNER + d];
        float dx = dv * xcv;
        float acc = 0.f;
#pragma unroll
        for (int n = 0; n < D_STATE; n++) {
            float a = exp2f(dv * Av2[n]);
            s[n] = a * s[n] + dx * Bs[l][n];
            acc += s[n] * Cs[l][n];
        }
        float zf = (float)xz[t*(2*D_INNER) + D_INNER + d];
        float g = zf / (1.f + __expf(-zf));
        y[t*D_INNER + d] = (bf16_t)((acc + xcv * Dv) * g);
    }
}

extern "C" void kernel_launch(void* const* d_in, const int* in_sizes, int n_in,
                              void* d_out, int out_size, void* d_ws, size_t ws_size,
                              hipStream_t stream) {
    const float* x          = (const float*)d_in[0];
    const float* norm_w     = (const float*)d_in[1];
    const float* in_proj_w  = (const float*)d_in[2];
    const float* conv_w     = (const float*)d_in[3];
    const float* conv_b     = (const float*)d_in[4];
    const float* x_proj_w   = (const float*)d_in[5];
    const float* dt_proj_w  = (const float*)d_in[6];
    const float* dt_proj_b  = (const float*)d_in[7];
    const float* A_log      = (const float*)d_in[8];
    const float* Dw         = (const float*)d_in[9];
    const float* out_proj_w = (const float*)d_in[10];

    float* out0 = (float*)d_out;                       // x + out_proj(y)
    float* out1 = out0 + (size_t)NTOK * D_MODEL;       // residual copy

    const int n_inw = 2*D_INNER*D_MODEL;
    const int n_xpw = XPROJ_N*D_INNER;
    const int n_dtw = D_INNER*DT_RANK;
    const int n_opw = D_MODEL*D_INNER;
    const size_t n_chunkst = (size_t)NB*NCHUNK*D_INNER*D_STATE;

    char* ws = (char*)d_ws;
    bf16_t* w_in  = (bf16_t*)ws;  ws += (size_t)n_inw * sizeof(bf16_t);
    bf16_t* w_xp  = (bf16_t*)ws;  ws += (size_t)n_xpw * sizeof(bf16_t);
    bf16_t* w_dt  = (bf16_t*)ws;  ws += (size_t)n_dtw * sizeof(bf16_t);
    bf16_t* w_op  = (bf16_t*)ws;  ws += (size_t)n_opw * sizeof(bf16_t);
    bf16_t* h     = (bf16_t*)ws;  ws += (size_t)NTOK * D_MODEL   * sizeof(bf16_t);
    bf16_t* xz    = (bf16_t*)ws;  ws += (size_t)NTOK * 2*D_INNER * sizeof(bf16_t);
    bf16_t* xc    = (bf16_t*)ws;  ws += (size_t)NTOK * D_INNER   * sizeof(bf16_t);
    bf16_t* proj  = (bf16_t*)ws;  ws += (size_t)NTOK * XPROJ_N   * sizeof(bf16_t);
    bf16_t* delta = (bf16_t*)ws;  ws += (size_t)NTOK * D_INNER   * sizeof(bf16_t);
    bf16_t* y     = (bf16_t*)ws;  ws += (size_t)NTOK * D_INNER   * sizeof(bf16_t);
    float*  ch    = (float*)ws;   ws += n_chunkst * sizeof(float);
    float*  cP    = (float*)ws;   ws += n_chunkst * sizeof(float);

    // 0) weight fp32 -> bf16
    cvt_kernel<<<(n_inw+255)/256, 256, 0, stream>>>(in_proj_w,  w_in, n_inw);
    cvt_kernel<<<(n_xpw+255)/256, 256, 0, stream>>>(x_proj_w,   w_xp, n_xpw);
    cvt_kernel<<<(n_dtw+255)/256, 256, 0, stream>>>(dt_proj_w,  w_dt, n_dtw);
    cvt_kernel<<<(n_opw+255)/256, 256, 0, stream>>>(out_proj_w, w_op, n_opw);

    // 1) RMSNorm
    rmsnorm_kernel<<<NTOK, 256, 0, stream>>>(x, norm_w, h);
    // 2) in_proj
    gemm_nt<0><<<dim3(NTOK/64, (2*D_INNER)/64), 256, 0, stream>>>(
        h, D_MODEL, w_in, D_MODEL, xz, 2*D_INNER, 2*D_INNER, D_MODEL,
        nullptr, nullptr, nullptr);
    // 3) conv + SiLU
    conv_silu_kernel<<<NTOK, 256, 0, stream>>>(xz, conv_w, conv_b, xc);
    // 4) x_proj
    gemm_nt<0><<<dim3(NTOK/64, 2), 256, 0, stream>>>(
        xc, D_INNER, w_xp, D_INNER, proj, XPROJ_N, XPROJ_N, D_INNER,
        nullptr, nullptr, nullptr);
    // 5) dt_proj + softplus
    gemm_nt<1><<<dim3(NTOK/64, D_INNER/64), 256, 0, stream>>>(
        proj, XPROJ_N, w_dt, DT_RANK, delta, D_INNER, D_INNER, DT_RANK,
        dt_proj_b, nullptr, nullptr);
    // 6) chunked selective scan (16 states per thread)
    scan_part1<<<dim3(D_INNER/256, NCHUNK, NB), 256, 0, stream>>>(
        delta, xc, proj, A_log, ch, cP);
    scan_part2<<<(int)((size_t)NB*D_INNER*D_STATE/256), 256, 0, stream>>>(ch, cP);
    scan_part3<<<dim3(D_INNER/256, NCHUNK, NB), 256, 0, stream>>>(
        delta, xc, proj, xz, A_log, Dw, ch, y);
    // 7) out_proj + residual add; residual copy
    gemm_nt<2><<<dim3(NTOK/64, D_MODEL/64), 256, 0, stream>>>(
        y, D_INNER, w_op, D_INNER, out0, D_MODEL, D_MODEL, D_INNER,
        nullptr, x, out1);
}

// Round 5
// 328.369 us; speedup vs baseline: 5.5632x; 1.2731x over previous
//
#include <hip/hip_runtime.h>
#include <cstdint>
#include <cstddef>

typedef __bf16 bf16_t;
typedef __bf16 bf16x8 __attribute__((ext_vector_type(8)));
typedef float  f32x4  __attribute__((ext_vector_type(4)));

#define D_MODEL 768
#define D_INNER 1536
#define D_STATE 16
#define DT_RANK 48
#define NB      2
#define SEQ     2048
#define NTOK    (NB*SEQ)   // 4096
#define XPROJ_N (DT_RANK + 2*D_STATE)  // 80
#define LC      32
#define NCHUNK  (SEQ/LC)   // 64

// async global->LDS, 16B per lane; lds base must be wave-uniform, HW adds lane*16
typedef __attribute__((address_space(1))) void gvoid_t;
typedef __attribute__((address_space(3))) void lvoid_t;
__device__ __forceinline__ void g2lds16(const bf16_t* g, bf16_t* l) {
    __builtin_amdgcn_global_load_lds((gvoid_t*)g, (lvoid_t*)l, 16, 0, 0);
}

// ---------------- fp32 -> bf16 conversion (weights) ----------------
__global__ __launch_bounds__(256)
void cvt_kernel(const float* __restrict__ src, bf16_t* __restrict__ dst, int n) {
    int i = blockIdx.x * 256 + threadIdx.x;
    if (i < n) dst[i] = (bf16_t)src[i];
}

// ---------------- RMSNorm ----------------
__global__ __launch_bounds__(256)
void rmsnorm_kernel(const float* __restrict__ x, const float* __restrict__ w,
                    bf16_t* __restrict__ h) {
    int t = blockIdx.x;
    int tid = threadIdx.x;
    const float* xr = x + (size_t)t * D_MODEL;
    float v[3];
    float ss = 0.f;
#pragma unroll
    for (int i = 0; i < 3; i++) { v[i] = xr[tid + 256*i]; ss += v[i]*v[i]; }
#pragma unroll
    for (int off = 32; off >= 1; off >>= 1) ss += __shfl_down(ss, off);
    __shared__ float red[4];
    int lane = tid & 63, wv = tid >> 6;
    if (lane == 0) red[wv] = ss;
    __syncthreads();
    float tot = red[0] + red[1] + red[2] + red[3];
    float r = rsqrtf(tot * (1.f/(float)D_MODEL) + 1e-5f);
#pragma unroll
    for (int i = 0; i < 3; i++)
        h[(size_t)t*D_MODEL + tid + 256*i] = (bf16_t)(v[i] * r * w[tid + 256*i]);
}

// ---------------- 128x128 NT GEMM (m93/m97 structure) ----------------
// C[m,n] = sum_k A[m,k]*B[n,k]. Requires M%128==0, N%128==0, K%32==0.
// 256 threads = 4 waves; wave quadrant 64x64, 4x4 MFMA 16x16x32 tiles.
// MODE 0: C(bf16) = acc
// MODE 2: C(f32) = acc + resid; resid_out = resid
template<int MODE>
__global__ __launch_bounds__(256)
void gemm_nt128(const bf16_t* __restrict__ A, int lda,
                const bf16_t* __restrict__ B, int ldb,
                void* __restrict__ Cv, int ldc, int K,
                const float* __restrict__ resid, float* __restrict__ resid_out) {
    __shared__ __align__(16) bf16_t As[128*32];
    __shared__ __align__(16) bf16_t Bs[128*32];
    const int tid = threadIdx.x;
    const int wave = tid >> 6, lane = tid & 63;
    const int quad = lane >> 4, l16 = lane & 15;
    const int m0 = blockIdx.x * 128, n0 = blockIdx.y * 128;
    const int wr = (wave >> 1) * 64, wc = (wave & 1) * 64;

    // staging groups: g in [0,512), 8 bf16 each; row=g>>2, col8=(g&3)*8;
    // LDS offset = g*16B (contiguous in g => wave-uniform-base + lane*16 works)
    const int g0 = tid, g1 = tid + 256;
    const int r0 = g0 >> 2, c0 = (g0 & 3) << 3;
    const int r1 = g1 >> 2, c1 = (g1 & 3) << 3;

    f32x4 acc[4][4] = {};

    for (int k0 = 0; k0 < K; k0 += 32) {
        g2lds16(A + (size_t)(m0 + r0)*lda + k0 + c0, &As[wave*512]);
        g2lds16(A + (size_t)(m0 + r1)*lda + k0 + c1, &As[wave*512 + 2048]);
        g2lds16(B + (size_t)(n0 + r0)*ldb + k0 + c0, &Bs[wave*512]);
        g2lds16(B + (size_t)(n0 + r1)*ldb + k0 + c1, &Bs[wave*512 + 2048]);
        __syncthreads();

        bf16x8 af[4], bf[4];
#pragma unroll
        for (int i = 0; i < 4; i++)
            af[i] = *(const bf16x8*)&As[(wr + i*16 + l16)*32 + quad*8];
#pragma unroll
        for (int j = 0; j < 4; j++)
            bf[j] = *(const bf16x8*)&Bs[(wc + j*16 + l16)*32 + quad*8];
#pragma unroll
        for (int i = 0; i < 4; i++)
#pragma unroll
            for (int j = 0; j < 4; j++)
                acc[i][j] = __builtin_amdgcn_mfma_f32_16x16x32_bf16(af[i], bf[j], acc[i][j], 0, 0, 0);
        __syncthreads();
    }

#pragma unroll
    for (int i = 0; i < 4; i++) {
#pragma unroll
        for (int j = 0; j < 4; j++) {
            int n = n0 + wc + j*16 + l16;
#pragma unroll
            for (int rr = 0; rr < 4; rr++) {
                int m = m0 + wr + i*16 + quad*4 + rr;
                size_t idx = (size_t)m * ldc + n;
                float v = acc[i][j][rr];
                if (MODE == 2) {
                    float rx = resid[idx];
                    ((float*)Cv)[idx] = v + rx;
                    resid_out[idx] = rx;
                } else {
                    ((bf16_t*)Cv)[idx] = (bf16_t)v;
                }
            }
        }
    }
}

// ---------------- 64x64 NT GEMM (small shapes) ----------------
// MODE 0: C(bf16) = acc ; MODE 1: C(bf16) = softplus(acc + bias[n])
template<int MODE>
__global__ __launch_bounds__(256)
void gemm_nt(const bf16_t* __restrict__ A, int lda,
             const bf16_t* __restrict__ B, int ldb,
             void* __restrict__ Cv, int ldc, int N, int K,
             const float* __restrict__ bias) {
    __shared__ __align__(16) bf16_t As[64*32];
    __shared__ __align__(16) bf16_t Bs[64*32];
    const int tid = threadIdx.x;
    const int m0 = blockIdx.x * 64, n0 = blockIdx.y * 64;
    const int r  = tid >> 2, c8 = (tid & 3) << 3;
    const int wave = tid >> 6, lane = tid & 63;
    const int quad = lane >> 4, l16 = lane & 15;

    f32x4 acc[4] = {{0.f,0.f,0.f,0.f},{0.f,0.f,0.f,0.f},
                    {0.f,0.f,0.f,0.f},{0.f,0.f,0.f,0.f}};

    for (int k0 = 0; k0 < K; k0 += 32) {
        int gk = k0 + c8;
        uint4 va = {0u,0u,0u,0u};
        if (gk + 8 <= K)
            va = *(const uint4*)(A + (size_t)(m0 + r) * lda + gk);
        *(uint4*)&As[r*32 + c8] = va;

        uint4 vb = {0u,0u,0u,0u};
        int nr = n0 + r;
        if (nr < N && gk + 8 <= K)
            vb = *(const uint4*)(B + (size_t)nr * ldb + gk);
        *(uint4*)&Bs[r*32 + c8] = vb;

        __syncthreads();
        bf16x8 af = *(const bf16x8*)&As[(wave*16 + l16)*32 + quad*8];
#pragma unroll
        for (int nt = 0; nt < 4; nt++) {
            bf16x8 bfg = *(const bf16x8*)&Bs[(nt*16 + l16)*32 + quad*8];
            acc[nt] = __builtin_amdgcn_mfma_f32_16x16x32_bf16(af, bfg, acc[nt], 0, 0, 0);
        }
        __syncthreads();
    }

#pragma unroll
    for (int nt = 0; nt < 4; nt++) {
        int n = n0 + nt*16 + l16;
        if (n >= N) continue;
#pragma unroll
        for (int rr = 0; rr < 4; rr++) {
            int m = m0 + wave*16 + quad*4 + rr;
            float v = acc[nt][rr];
            size_t idx = (size_t)m * ldc + n;
            if (MODE == 1) {
                float u = v + bias[n];
                float sp = (u > 20.f) ? u : log1pf(__expf(u));
                ((bf16_t*)Cv)[idx] = (bf16_t)sp;
            } else {
                ((bf16_t*)Cv)[idx] = (bf16_t)v;
            }
        }
    }
}

// ---------------- causal depthwise conv(4) + SiLU ----------------
__global__ __launch_bounds__(256)
void conv_silu_kernel(const bf16_t* __restrict__ xz,
                      const float* __restrict__ cw,
                      const float* __restrict__ cb,
                      bf16_t* __restrict__ xc) {
    int t = blockIdx.x;
    int l = t & (SEQ - 1);
    for (int d = threadIdx.x; d < D_INNER; d += 256) {
        float acc = cb[d];
#pragma unroll
        for (int k = 0; k < 4; k++) {
            int ll = l - 3 + k;
            if (ll >= 0)
                acc += (float)xz[(size_t)(t - 3 + k) * (2*D_INNER) + d] * cw[d*4 + k];
        }
        float s = acc / (1.f + __expf(-acc));
        xc[(size_t)t * D_INNER + d] = (bf16_t)s;
    }
}

// ---------------- chunked selective scan, 16 states/thread ----------------
__global__ __launch_bounds__(256)
void scan_part1(const bf16_t* __restrict__ delta,
                const bf16_t* __restrict__ xc,
                const bf16_t* __restrict__ proj,
                const float* __restrict__ A_log,
                float* __restrict__ chunk_h, float* __restrict__ chunk_P) {
    const int tid = threadIdx.x;
    const int d = blockIdx.x * 256 + tid;
    const int c = blockIdx.y;
    const int b = blockIdx.z;
    __shared__ float Bs[LC][D_STATE];
    for (int i = tid; i < LC*D_STATE; i += 256) {
        int l = i >> 4, n = i & 15;
        size_t t = (size_t)b*SEQ + (size_t)c*LC + l;
        Bs[l][n] = (float)proj[t*XPROJ_N + DT_RANK + n];
    }
    __syncthreads();
    float Av2[D_STATE];
#pragma unroll
    for (int n = 0; n < D_STATE; n++)
        Av2[n] = -__expf(A_log[d*D_STATE + n]) * 1.44269504f;   // A[n]*log2(e)
    float s[D_STATE], P[D_STATE];
#pragma unroll
    for (int n = 0; n < D_STATE; n++) { s[n] = 0.f; P[n] = 1.f; }
    const size_t tbase = (size_t)b*SEQ + (size_t)c*LC;
    for (int l = 0; l < LC; l++) {
        size_t t = tbase + l;
        float dv  = (float)delta[t*D_INNER + d];
        float xcv = (float)xc[t*D_INNER + d];
        float dx = dv * xcv;
#pragma unroll
        for (int n = 0; n < D_STATE; n++) {
            float a = __builtin_amdgcn_exp2f(dv * Av2[n]);
            s[n] = a * s[n] + dx * Bs[l][n];
            P[n] *= a;
        }
    }
    size_t base = (((size_t)b*NCHUNK + c)*D_INNER + d)*D_STATE;
#pragma unroll
    for (int n = 0; n < D_STATE; n++) {
        chunk_h[base + n] = s[n];
        chunk_P[base + n] = P[n];
    }
}

__global__ __launch_bounds__(256)
void scan_part2(float* __restrict__ chunk_h, const float* __restrict__ chunk_P) {
    int gid = blockIdx.x * 256 + threadIdx.x;      // b*(Di*N) + d*N + n
    int b  = gid / (D_INNER * D_STATE);
    int dn = gid - b * (D_INNER * D_STATE);
    float H = 0.f;
    for (int c = 0; c < NCHUNK; c++) {
        size_t idx = ((size_t)b*NCHUNK + c)*D_INNER*D_STATE + dn;
        float S = chunk_h[idx];
        float P = chunk_P[idx];
        chunk_h[idx] = H;          // becomes the initial state for chunk c
        H = P * H + S;
    }
}

__global__ __launch_bounds__(256)
void scan_part3(const bf16_t* __restrict__ delta,
                const bf16_t* __restrict__ xc,
                const bf16_t* __restrict__ proj,
                const bf16_t* __restrict__ xz,
                const float* __restrict__ A_log,
                const float* __restrict__ Dw,
                const float* __restrict__ chunk_h,
                bf16_t* __restrict__ y) {
    const int tid = threadIdx.x;
    const int d = blockIdx.x * 256 + tid;
    const int c = blockIdx.y;
    const int b = blockIdx.z;
    __shared__ float Bs[LC][D_STATE];
    __shared__ float Cs[LC][D_STATE];
    for (int i = tid; i < LC*D_STATE; i += 256) {
        int l = i >> 4, n = i & 15;
        size_t t = (size_t)b*SEQ + (size_t)c*LC + l;
        Bs[l][n] = (float)proj[t*XPROJ_N + DT_RANK + n];
        Cs[l][n] = (float)proj[t*XPROJ_N + DT_RANK + D_STATE + n];
    }
    __syncthreads();
    float Av2[D_STATE];
#pragma unroll
    for (int n = 0; n < D_STATE; n++)
        Av2[n] = -__expf(A_log[d*D_STATE + n]) * 1.44269504f;
    const float Dv = Dw[d];
    float s[D_STATE];
    size_t base = (((size_t)b*NCHUNK + c)*D_INNER + d)*D_STATE;
#pragma unroll
    for (int n = 0; n < D_STATE; n++) s[n] = chunk_h[base + n];
    const size_t tbase = (size_t)b*SEQ + (size_t)c*LC;
    for (int l = 0; l < LC; l++) {
        size_t t = tbase + l;
        float dv  = (float)delta[t*D_INNER + d];
        float xcv = (float)xc[t*D_INNER + d];
        float dx = dv * xcv;
        float acc = 0.f;
#pragma unroll
        for (int n = 0; n < D_STATE; n++) {
            float a = __builtin_amdgcn_exp2f(dv * Av2[n]);
            s[n] = a * s[n] + dx * Bs[l][n];
            acc += s[n] * Cs[l][n];
        }
        float zf = (float)xz[t*(2*D_INNER) + D_INNER + d];
        float g = zf / (1.f + __expf(-zf));
        y[t*D_INNER + d] = (bf16_t)((acc + xcv * Dv) * g);
    }
}

extern "C" void kernel_launch(void* const* d_in, const int* in_sizes, int n_in,
                              void* d_out, int out_size, void* d_ws, size_t ws_size,
                              hipStream_t stream) {
    const float* x          = (const float*)d_in[0];
    const float* norm_w     = (const float*)d_in[1];
    const float* in_proj_w  = (const float*)d_in[2];
    const float* conv_w     = (const float*)d_in[3];
    const float* conv_b     = (const float*)d_in[4];
    const float* x_proj_w   = (const float*)d_in[5];
    const float* dt_proj_w  = (const float*)d_in[6];
    const float* dt_proj_b  = (const float*)d_in[7];
    const float* A_log      = (const float*)d_in[8];
    const float* Dw         = (const float*)d_in[9];
    const float* out_proj_w = (const float*)d_in[10];

    float* out0 = (float*)d_out;                       // x + out_proj(y)
    float* out1 = out0 + (size_t)NTOK * D_MODEL;       // residual copy

    const int n_inw = 2*D_INNER*D_MODEL;
    const int n_xpw = XPROJ_N*D_INNER;
    const int n_dtw = D_INNER*DT_RANK;
    const int n_opw = D_MODEL*D_INNER;
    const size_t n_chunkst = (size_t)NB*NCHUNK*D_INNER*D_STATE;

    char* ws = (char*)d_ws;
    bf16_t* w_in  = (bf16_t*)ws;  ws += (size_t)n_inw * sizeof(bf16_t);
    bf16_t* w_xp  = (bf16_t*)ws;  ws += (size_t)n_xpw * sizeof(bf16_t);
    bf16_t* w_dt  = (bf16_t*)ws;  ws += (size_t)n_dtw * sizeof(bf16_t);
    bf16_t* w_op  = (bf16_t*)ws;  ws += (size_t)n_opw * sizeof(bf16_t);
    bf16_t* h     = (bf16_t*)ws;  ws += (size_t)NTOK * D_MODEL   * sizeof(bf16_t);
    bf16_t* xz    = (bf16_t*)ws;  ws += (size_t)NTOK * 2*D_INNER * sizeof(bf16_t);
    bf16_t* xc    = (bf16_t*)ws;  ws += (size_t)NTOK * D_INNER   * sizeof(bf16_t);
    bf16_t* proj  = (bf16_t*)ws;  ws += (size_t)NTOK * XPROJ_N   * sizeof(bf16_t);
    bf16_t* delta = (bf16_t*)ws;  ws += (size_t)NTOK * D_INNER   * sizeof(bf16_t);
    bf16_t* y     = (bf16_t*)ws;  ws += (size_t)NTOK * D_INNER   * sizeof(bf16_t);
    float*  ch    = (float*)ws;   ws += n_chunkst * sizeof(float);
    float*  cP    = (float*)ws;   ws += n_chunkst * sizeof(float);

    // 0) weight fp32 -> bf16
    cvt_kernel<<<(n_inw+255)/256, 256, 0, stream>>>(in_proj_w,  w_in, n_inw);
    cvt_kernel<<<(n_xpw+255)/256, 256, 0, stream>>>(x_proj_w,   w_xp, n_xpw);
    cvt_kernel<<<(n_dtw+255)/256, 256, 0, stream>>>(dt_proj_w,  w_dt, n_dtw);
    cvt_kernel<<<(n_opw+255)/256, 256, 0, stream>>>(out_proj_w, w_op, n_opw);

    // 1) RMSNorm
    rmsnorm_kernel<<<NTOK, 256, 0, stream>>>(x, norm_w, h);
    // 2) in_proj: [4096,768] x [3072,768]^T -> xz, 128-tile async
    gemm_nt128<0><<<dim3(NTOK/128, (2*D_INNER)/128), 256, 0, stream>>>(
        h, D_MODEL, w_in, D_MODEL, xz, 2*D_INNER, D_MODEL, nullptr, nullptr);
    // 3) conv + SiLU
    conv_silu_kernel<<<NTOK, 256, 0, stream>>>(xz, conv_w, conv_b, xc);
    // 4) x_proj (small N)
    gemm_nt<0><<<dim3(NTOK/64, 2), 256, 0, stream>>>(
        xc, D_INNER, w_xp, D_INNER, proj, XPROJ_N, XPROJ_N, D_INNER, nullptr);
    // 5) dt_proj + softplus (tiny K)
    gemm_nt<1><<<dim3(NTOK/64, D_INNER/64), 256, 0, stream>>>(
        proj, XPROJ_N, w_dt, DT_RANK, delta, D_INNER, D_INNER, DT_RANK, dt_proj_b);
    // 6) chunked selective scan (16 states per thread, LC=32)
    scan_part1<<<dim3(D_INNER/256, NCHUNK, NB), 256, 0, stream>>>(
        delta, xc, proj, A_log, ch, cP);
    scan_part2<<<(int)((size_t)NB*D_INNER*D_STATE/256), 256, 0, stream>>>(ch, cP);
    scan_part3<<<dim3(D_INNER/256, NCHUNK, NB), 256, 0, stream>>>(
        delta, xc, proj, xz, A_log, Dw, ch, y);
    // 7) out_proj + residual add, 128-tile async
    gemm_nt128<2><<<dim3(NTOK/128, D_MODEL/128), 256, 0, stream>>>(
        y, D_INNER, w_op, D_INNER, out0, D_MODEL, D_INNER, x, out1);
}

// Round 6
// 319.132 us; speedup vs baseline: 5.7242x; 1.0289x over previous
//
#include <hip/hip_runtime.h>
#include <cstdint>
#include <cstddef>

typedef __bf16 bf16_t;
typedef __bf16 bf16x8 __attribute__((ext_vector_type(8)));
typedef float  f32x4  __attribute__((ext_vector_type(4)));

#define D_MODEL 768
#define D_INNER 1536
#define D_STATE 16
#define DT_RANK 48
#define NB      2
#define SEQ     2048
#define NTOK    (NB*SEQ)   // 4096
#define XPROJ_N (DT_RANK + 2*D_STATE)  // 80
#define LC      32
#define NCHUNK  (SEQ/LC)   // 64

// async global->LDS, 16B per lane; lds base must be wave-uniform, HW adds lane*16
typedef __attribute__((address_space(1))) void gvoid_t;
typedef __attribute__((address_space(3))) void lvoid_t;
__device__ __forceinline__ void g2lds16(const bf16_t* g, bf16_t* l) {
    __builtin_amdgcn_global_load_lds((gvoid_t*)g, (lvoid_t*)l, 16, 0, 0);
}

// ---------------- fp32 -> bf16 conversion, all 4 weights in one launch ----------------
__global__ __launch_bounds__(256)
void cvt4_kernel(const float* __restrict__ s0, bf16_t* __restrict__ d0, int n0,
                 const float* __restrict__ s1, bf16_t* __restrict__ d1, int n1,
                 const float* __restrict__ s2, bf16_t* __restrict__ d2, int n2,
                 const float* __restrict__ s3, bf16_t* __restrict__ d3, int n3) {
    int i = blockIdx.x * 256 + threadIdx.x;
    if (i < n0) { d0[i] = (bf16_t)s0[i]; return; }
    i -= n0;
    if (i < n1) { d1[i] = (bf16_t)s1[i]; return; }
    i -= n1;
    if (i < n2) { d2[i] = (bf16_t)s2[i]; return; }
    i -= n2;
    if (i < n3) { d3[i] = (bf16_t)s3[i]; }
}

// ---------------- RMSNorm ----------------
__global__ __launch_bounds__(256)
void rmsnorm_kernel(const float* __restrict__ x, const float* __restrict__ w,
                    bf16_t* __restrict__ h) {
    int t = blockIdx.x;
    int tid = threadIdx.x;
    const float* xr = x + (size_t)t * D_MODEL;
    float v[3];
    float ss = 0.f;
#pragma unroll
    for (int i = 0; i < 3; i++) { v[i] = xr[tid + 256*i]; ss += v[i]*v[i]; }
#pragma unroll
    for (int off = 32; off >= 1; off >>= 1) ss += __shfl_down(ss, off);
    __shared__ float red[4];
    int lane = tid & 63, wv = tid >> 6;
    if (lane == 0) red[wv] = ss;
    __syncthreads();
    float tot = red[0] + red[1] + red[2] + red[3];
    float r = rsqrtf(tot * (1.f/(float)D_MODEL) + 1e-5f);
#pragma unroll
    for (int i = 0; i < 3; i++)
        h[(size_t)t*D_MODEL + tid + 256*i] = (bf16_t)(v[i] * r * w[tid + 256*i]);
}

// ---------------- 128x128 NT GEMM, bank-conflict-free swizzled LDS ----------------
// C[m,n] = sum_k A[m,k]*B[n,k]. Requires M%128==0, N%128==0, K%32==0.
// LDS layout: row stride 32 bf16; row r's logical 8-elem k-chunk q stored at
// position p = q ^ ((r>>1)&3). global_load_lds stays contiguous (slot s =
// wave*64+lane); the *global* source chunk is swizzled instead. ds_read_b128
// slots then cover all 8 16B chunk-slots evenly -> 2-way aliasing (free).
// MODE 0: C(bf16) = acc
// MODE 2: C(f32) = acc + resid; resid_out = resid
template<int MODE>
__global__ __launch_bounds__(256)
void gemm_nt128(const bf16_t* __restrict__ A, int lda,
                const bf16_t* __restrict__ B, int ldb,
                void* __restrict__ Cv, int ldc, int K,
                const float* __restrict__ resid, float* __restrict__ resid_out) {
    __shared__ __align__(16) bf16_t As[128*32];
    __shared__ __align__(16) bf16_t Bs[128*32];
    const int tid = threadIdx.x;
    const int wave = tid >> 6, lane = tid & 63;
    const int quad = lane >> 4, l16 = lane & 15;
    const int m0 = blockIdx.x * 128, n0 = blockIdx.y * 128;
    const int wr = (wave >> 1) * 64, wc = (wave & 1) * 64;

    // staging: slot s in [0,512) holds row s>>2, stored-chunk-position s&3;
    // the global chunk loaded there is q = (s&3) ^ ((row>>1)&3)
    const int s0 = tid, s1 = tid + 256;
    const int r0 = s0 >> 2, q0 = ((s0 & 3) ^ ((r0 >> 1) & 3)) << 3;
    const int r1 = s1 >> 2, q1 = ((s1 & 3) ^ ((r1 >> 1) & 3)) << 3;

    f32x4 acc[4][4] = {};

    for (int k0 = 0; k0 < K; k0 += 32) {
        g2lds16(A + (size_t)(m0 + r0)*lda + k0 + q0, &As[wave*512]);
        g2lds16(A + (size_t)(m0 + r1)*lda + k0 + q1, &As[wave*512 + 2048]);
        g2lds16(B + (size_t)(n0 + r0)*ldb + k0 + q0, &Bs[wave*512]);
        g2lds16(B + (size_t)(n0 + r1)*ldb + k0 + q1, &Bs[wave*512 + 2048]);
        __syncthreads();

        bf16x8 af[4], bfr[4];
#pragma unroll
        for (int i = 0; i < 4; i++) {
            int rr = wr + i*16 + l16;
            af[i] = *(const bf16x8*)&As[rr*32 + ((quad ^ ((rr >> 1) & 3)) << 3)];
        }
#pragma unroll
        for (int j = 0; j < 4; j++) {
            int rr = wc + j*16 + l16;
            bfr[j] = *(const bf16x8*)&Bs[rr*32 + ((quad ^ ((rr >> 1) & 3)) << 3)];
        }
#pragma unroll
        for (int i = 0; i < 4; i++)
#pragma unroll
            for (int j = 0; j < 4; j++)
                acc[i][j] = __builtin_amdgcn_mfma_f32_16x16x32_bf16(af[i], bfr[j], acc[i][j], 0, 0, 0);
        __syncthreads();
    }

#pragma unroll
    for (int i = 0; i < 4; i++) {
#pragma unroll
        for (int j = 0; j < 4; j++) {
            int n = n0 + wc + j*16 + l16;
#pragma unroll
            for (int rr = 0; rr < 4; rr++) {
                int m = m0 + wr + i*16 + quad*4 + rr;
                size_t idx = (size_t)m * ldc + n;
                float v = acc[i][j][rr];
                if (MODE == 2) {
                    float rx = resid[idx];
                    ((float*)Cv)[idx] = v + rx;
                    resid_out[idx] = rx;
                } else {
                    ((bf16_t*)Cv)[idx] = (bf16_t)v;
                }
            }
        }
    }
}

// ---------------- 64x64 NT GEMM (small shapes), same swizzle ----------------
// MODE 0: C(bf16) = acc ; MODE 1: C(bf16) = softplus(acc + bias[n])
template<int MODE>
__global__ __launch_bounds__(256)
void gemm_nt(const bf16_t* __restrict__ A, int lda,
             const bf16_t* __restrict__ B, int ldb,
             void* __restrict__ Cv, int ldc, int N, int K,
             const float* __restrict__ bias) {
    __shared__ __align__(16) bf16_t As[64*32];
    __shared__ __align__(16) bf16_t Bs[64*32];
    const int tid = threadIdx.x;
    const int m0 = blockIdx.x * 64, n0 = blockIdx.y * 64;
    const int r  = tid >> 2, p8 = (tid & 3) << 3;
    const int q8 = (((tid & 3) ^ ((r >> 1) & 3)) << 3);   // swizzled global chunk
    const int wave = tid >> 6, lane = tid & 63;
    const int quad = lane >> 4, l16 = lane & 15;

    f32x4 acc[4] = {{0.f,0.f,0.f,0.f},{0.f,0.f,0.f,0.f},
                    {0.f,0.f,0.f,0.f},{0.f,0.f,0.f,0.f}};

    for (int k0 = 0; k0 < K; k0 += 32) {
        int gk = k0 + q8;
        uint4 va = {0u,0u,0u,0u};
        if (gk + 8 <= K)
            va = *(const uint4*)(A + (size_t)(m0 + r) * lda + gk);
        *(uint4*)&As[r*32 + p8] = va;

        uint4 vb = {0u,0u,0u,0u};
        int nr = n0 + r;
        if (nr < N && gk + 8 <= K)
            vb = *(const uint4*)(B + (size_t)nr * ldb + gk);
        *(uint4*)&Bs[r*32 + p8] = vb;

        __syncthreads();
        int ra = wave*16 + l16;
        bf16x8 af = *(const bf16x8*)&As[ra*32 + ((quad ^ ((ra >> 1) & 3)) << 3)];
#pragma unroll
        for (int nt = 0; nt < 4; nt++) {
            int rb = nt*16 + l16;
            bf16x8 bfg = *(const bf16x8*)&Bs[rb*32 + ((quad ^ ((rb >> 1) & 3)) << 3)];
            acc[nt] = __builtin_amdgcn_mfma_f32_16x16x32_bf16(af, bfg, acc[nt], 0, 0, 0);
        }
        __syncthreads();
    }

#pragma unroll
    for (int nt = 0; nt < 4; nt++) {
        int n = n0 + nt*16 + l16;
        if (n >= N) continue;
#pragma unroll
        for (int rr = 0; rr < 4; rr++) {
            int m = m0 + wave*16 + quad*4 + rr;
            float v = acc[nt][rr];
            size_t idx = (size_t)m * ldc + n;
            if (MODE == 1) {
                float u = v + bias[n];
                float sp = (u > 20.f) ? u : log1pf(__expf(u));
                ((bf16_t*)Cv)[idx] = (bf16_t)sp;
            } else {
                ((bf16_t*)Cv)[idx] = (bf16_t)v;
            }
        }
    }
}

// ---------------- causal depthwise conv(4) + SiLU ----------------
__global__ __launch_bounds__(256)
void conv_silu_kernel(const bf16_t* __restrict__ xz,
                      const float* __restrict__ cw,
                      const float* __restrict__ cb,
                      bf16_t* __restrict__ xc) {
    int t = blockIdx.x;
    int l = t & (SEQ - 1);
    for (int d = threadIdx.x; d < D_INNER; d += 256) {
        float acc = cb[d];
#pragma unroll
        for (int k = 0; k < 4; k++) {
            int ll = l - 3 + k;
            if (ll >= 0)
                acc += (float)xz[(size_t)(t - 3 + k) * (2*D_INNER) + d] * cw[d*4 + k];
        }
        float s = acc / (1.f + __expf(-acc));
        xc[(size_t)t * D_INNER + d] = (bf16_t)s;
    }
}

// ---------------- chunked selective scan, 16 states/thread ----------------
__global__ __launch_bounds__(256)
void scan_part1(const bf16_t* __restrict__ delta,
                const bf16_t* __restrict__ xc,
                const bf16_t* __restrict__ proj,
                const float* __restrict__ A_log,
                float* __restrict__ chunk_h, float* __restrict__ chunk_P) {
    const int tid = threadIdx.x;
    const int d = blockIdx.x * 256 + tid;
    const int c = blockIdx.y;
    const int b = blockIdx.z;
    __shared__ float Bs[LC][D_STATE];
    for (int i = tid; i < LC*D_STATE; i += 256) {
        int l = i >> 4, n = i & 15;
        size_t t = (size_t)b*SEQ + (size_t)c*LC + l;
        Bs[l][n] = (float)proj[t*XPROJ_N + DT_RANK + n];
    }
    __syncthreads();
    float Av2[D_STATE];
#pragma unroll
    for (int n = 0; n < D_STATE; n++)
        Av2[n] = -__expf(A_log[d*D_STATE + n]) * 1.44269504f;   // A[n]*log2(e)
    float s[D_STATE], P[D_STATE];
#pragma unroll
    for (int n = 0; n < D_STATE; n++) { s[n] = 0.f; P[n] = 1.f; }
    const size_t tbase = (size_t)b*SEQ + (size_t)c*LC;
    for (int l = 0; l < LC; l++) {
        size_t t = tbase + l;
        float dv  = (float)delta[t*D_INNER + d];
        float xcv = (float)xc[t*D_INNER + d];
        float dx = dv * xcv;
#pragma unroll
        for (int n = 0; n < D_STATE; n++) {
            float a = __builtin_amdgcn_exp2f(dv * Av2[n]);
            s[n] = a * s[n] + dx * Bs[l][n];
            P[n] *= a;
        }
    }
    size_t base = (((size_t)b*NCHUNK + c)*D_INNER + d)*D_STATE;
#pragma unroll
    for (int n = 0; n < D_STATE; n++) {
        chunk_h[base + n] = s[n];
        chunk_P[base + n] = P[n];
    }
}

__global__ __launch_bounds__(256)
void scan_part2(float* __restrict__ chunk_h, const float* __restrict__ chunk_P) {
    int gid = blockIdx.x * 256 + threadIdx.x;      // b*(Di*N) + d*N + n
    int b  = gid / (D_INNER * D_STATE);
    int dn = gid - b * (D_INNER * D_STATE);
    float H = 0.f;
    for (int c = 0; c < NCHUNK; c++) {
        size_t idx = ((size_t)b*NCHUNK + c)*D_INNER*D_STATE + dn;
        float S = chunk_h[idx];
        float P = chunk_P[idx];
        chunk_h[idx] = H;          // becomes the initial state for chunk c
        H = P * H + S;
    }
}

__global__ __launch_bounds__(256)
void scan_part3(const bf16_t* __restrict__ delta,
                const bf16_t* __restrict__ xc,
                const bf16_t* __restrict__ proj,
                const bf16_t* __restrict__ xz,
                const float* __restrict__ A_log,
                const float* __restrict__ Dw,
                const float* __restrict__ chunk_h,
                bf16_t* __restrict__ y) {
    const int tid = threadIdx.x;
    const int d = blockIdx.x * 256 + tid;
    const int c = blockIdx.y;
    const int b = blockIdx.z;
    __shared__ float Bs[LC][D_STATE];
    __shared__ float Cs[LC][D_STATE];
    for (int i = tid; i < LC*D_STATE; i += 256) {
        int l = i >> 4, n = i & 15;
        size_t t = (size_t)b*SEQ + (size_t)c*LC + l;
        Bs[l][n] = (float)proj[t*XPROJ_N + DT_RANK + n];
        Cs[l][n] = (float)proj[t*XPROJ_N + DT_RANK + D_STATE + n];
    }
    __syncthreads();
    float Av2[D_STATE];
#pragma unroll
    for (int n = 0; n < D_STATE; n++)
        Av2[n] = -__expf(A_log[d*D_STATE + n]) * 1.44269504f;
    const float Dv = Dw[d];
    float s[D_STATE];
    size_t base = (((size_t)b*NCHUNK + c)*D_INNER + d)*D_STATE;
#pragma unroll
    for (int n = 0; n < D_STATE; n++) s[n] = chunk_h[base + n];
    const size_t tbase = (size_t)b*SEQ + (size_t)c*LC;
    for (int l = 0; l < LC; l++) {
        size_t t = tbase + l;
        float dv  = (float)delta[t*D_INNER + d];
        float xcv = (float)xc[t*D_INNER + d];
        float dx = dv * xcv;
        float acc = 0.f;
#pragma unroll
        for (int n = 0; n < D_STATE; n++) {
            float a = __builtin_amdgcn_exp2f(dv * Av2[n]);
            s[n] = a * s[n] + dx * Bs[l][n];
            acc += s[n] * Cs[l][n];
        }
        float zf = (float)xz[t*(2*D_INNER) + D_INNER + d];
        float g = zf / (1.f + __expf(-zf));
        y[t*D_INNER + d] = (bf16_t)((acc + xcv * Dv) * g);
    }
}

extern "C" void kernel_launch(void* const* d_in, const int* in_sizes, int n_in,
                              void* d_out, int out_size, void* d_ws, size_t ws_size,
                              hipStream_t stream) {
    const float* x          = (const float*)d_in[0];
    const float* norm_w     = (const float*)d_in[1];
    const float* in_proj_w  = (const float*)d_in[2];
    const float* conv_w     = (const float*)d_in[3];
    const float* conv_b     = (const float*)d_in[4];
    const float* x_proj_w   = (const float*)d_in[5];
    const float* dt_proj_w  = (const float*)d_in[6];
    const float* dt_proj_b  = (const float*)d_in[7];
    const float* A_log      = (const float*)d_in[8];
    const float* Dw         = (const float*)d_in[9];
    const float* out_proj_w = (const float*)d_in[10];

    float* out0 = (float*)d_out;                       // x + out_proj(y)
    float* out1 = out0 + (size_t)NTOK * D_MODEL;       // residual copy

    const int n_inw = 2*D_INNER*D_MODEL;
    const int n_xpw = XPROJ_N*D_INNER;
    const int n_dtw = D_INNER*DT_RANK;
    const int n_opw = D_MODEL*D_INNER;
    const size_t n_chunkst = (size_t)NB*NCHUNK*D_INNER*D_STATE;

    char* ws = (char*)d_ws;
    bf16_t* w_in  = (bf16_t*)ws;  ws += (size_t)n_inw * sizeof(bf16_t);
    bf16_t* w_xp  = (bf16_t*)ws;  ws += (size_t)n_xpw * sizeof(bf16_t);
    bf16_t* w_dt  = (bf16_t*)ws;  ws += (size_t)n_dtw * sizeof(bf16_t);
    bf16_t* w_op  = (bf16_t*)ws;  ws += (size_t)n_opw * sizeof(bf16_t);
    bf16_t* h     = (bf16_t*)ws;  ws += (size_t)NTOK * D_MODEL   * sizeof(bf16_t);
    bf16_t* xz    = (bf16_t*)ws;  ws += (size_t)NTOK * 2*D_INNER * sizeof(bf16_t);
    bf16_t* xc    = (bf16_t*)ws;  ws += (size_t)NTOK * D_INNER   * sizeof(bf16_t);
    bf16_t* proj  = (bf16_t*)ws;  ws += (size_t)NTOK * XPROJ_N   * sizeof(bf16_t);
    bf16_t* delta = (bf16_t*)ws;  ws += (size_t)NTOK * D_INNER   * sizeof(bf16_t);
    bf16_t* y     = (bf16_t*)ws;  ws += (size_t)NTOK * D_INNER   * sizeof(bf16_t);
    float*  ch    = (float*)ws;   ws += n_chunkst * sizeof(float);
    float*  cP    = (float*)ws;   ws += n_chunkst * sizeof(float);

    // 0) weight fp32 -> bf16 (single launch)
    const int n_cvt = n_inw + n_xpw + n_dtw + n_opw;
    cvt4_kernel<<<(n_cvt+255)/256, 256, 0, stream>>>(
        in_proj_w, w_in, n_inw, x_proj_w, w_xp, n_xpw,
        dt_proj_w, w_dt, n_dtw, out_proj_w, w_op, n_opw);

    // 1) RMSNorm
    rmsnorm_kernel<<<NTOK, 256, 0, stream>>>(x, norm_w, h);
    // 2) in_proj: [4096,768] x [3072,768]^T -> xz, 128-tile async swizzled
    gemm_nt128<0><<<dim3(NTOK/128, (2*D_INNER)/128), 256, 0, stream>>>(
        h, D_MODEL, w_in, D_MODEL, xz, 2*D_INNER, D_MODEL, nullptr, nullptr);
    // 3) conv + SiLU
    conv_silu_kernel<<<NTOK, 256, 0, stream>>>(xz, conv_w, conv_b, xc);
    // 4) x_proj (small N)
    gemm_nt<0><<<dim3(NTOK/64, 2), 256, 0, stream>>>(
        xc, D_INNER, w_xp, D_INNER, proj, XPROJ_N, XPROJ_N, D_INNER, nullptr);
    // 5) dt_proj + softplus (tiny K)
    gemm_nt<1><<<dim3(NTOK/64, D_INNER/64), 256, 0, stream>>>(
        proj, XPROJ_N, w_dt, DT_RANK, delta, D_INNER, D_INNER, DT_RANK, dt_proj_b);
    // 6) chunked selective scan (16 states per thread, LC=32)
    scan_part1<<<dim3(D_INNER/256, NCHUNK, NB), 256, 0, stream>>>(
        delta, xc, proj, A_log, ch, cP);
    scan_part2<<<(int)((size_t)NB*D_INNER*D_STATE/256), 256, 0, stream>>>(ch, cP);
    scan_part3<<<dim3(D_INNER/256, NCHUNK, NB), 256, 0, stream>>>(
        delta, xc, proj, xz, A_log, Dw, ch, y);
    // 7) out_proj + residual add, 128-tile async swizzled
    gemm_nt128<2><<<dim3(NTOK/128, D_MODEL/128), 256, 0, stream>>>(
        y, D_INNER, w_op, D_INNER, out0, D_MODEL, D_INNER, x, out1);
}